// Round 17
// baseline (175.646 us; speedup 1.0000x reference)
//
#include <hip/hip_runtime.h>
#include <stdint.h>

typedef __attribute__((ext_vector_type(8))) short short8;
typedef __attribute__((ext_vector_type(4))) float f32x4;
typedef __attribute__((ext_vector_type(8))) unsigned short u16x8;
typedef __attribute__((ext_vector_type(2))) unsigned int u32x2;

#define DEV static __device__ __forceinline__

DEV unsigned short f2bf(float f) {
  union { float f; uint32_t u; } v; v.f = f;
  uint32_t r = v.u + 0x7FFFu + ((v.u >> 16) & 1u);
  return (unsigned short)(r >> 16);
}

DEV void gload16(const void* g, void* l) {
  __builtin_amdgcn_global_load_lds(
      (const __attribute__((address_space(1))) void*)g,
      (__attribute__((address_space(3))) void*)l, 16, 0, 0);
}

// ---------------- fused prep: cast x (blocks 0..4095) + transpose W (4096..5119) ----
__global__ __launch_bounds__(256) void prep_kernel(const float* __restrict__ x,
                                                   unsigned short* __restrict__ xb,
                                                   const float* __restrict__ Wq,
                                                   const float* __restrict__ Wk,
                                                   const float* __restrict__ Wv,
                                                   const float* __restrict__ Wo,
                                                   unsigned short* __restrict__ wt) {
  __shared__ float tile[64][65];
  int t = threadIdx.x;
  if (blockIdx.x < 4096) {
    int i = blockIdx.x * 256 + t;
    f32x4 a = ((const f32x4*)x)[2 * i];
    f32x4 b = ((const f32x4*)x)[2 * i + 1];
    u16x8 o;
    o[0] = f2bf(a[0]); o[1] = f2bf(a[1]); o[2] = f2bf(a[2]); o[3] = f2bf(a[3]);
    o[4] = f2bf(b[0]); o[5] = f2bf(b[1]); o[6] = f2bf(b[2]); o[7] = f2bf(b[3]);
    ((u16x8*)xb)[i] = o;
    return;
  }
  int flat = blockIdx.x - 4096;
  int bn = flat & 15, bk = (flat >> 4) & 15, z = flat >> 8;
  const float* W = (z == 0) ? Wq : (z == 1) ? Wk : (z == 2) ? Wv : Wo;
  unsigned short* dst = wt + (size_t)z * 1024 * 1024;
  int c = t & 63, rr = t >> 6;
#pragma unroll
  for (int p = 0; p < 16; ++p) {
    int r = p * 4 + rr;
    tile[r][c] = W[(size_t)(bk * 64 + r) * 1024 + bn * 64 + c];
  }
  __syncthreads();
#pragma unroll
  for (int p = 0; p < 16; ++p) {
    int r2 = p * 4 + rr;
    dst[(size_t)(bn * 64 + r2) * 1024 + bk * 64 + c] = f2bf(tile[c][r2]);
  }
}

// ---------------- fused QKV GEMM: 256x256 tile, 8 waves, 4-phase deep pipeline ----
// C(8192 x 3072) = xb(8192x1024) * [Wq|Wk|Wv]^T. Grid 384 blocks, 128KB LDS,
// 1 block/CU. Per K-tile t (BK=64): 4 phases (one C-quadrant = 2m x 4n x 2kk
// = 16 MFMA each; 2 barriers/phase). Staging (verified by per-wave queue walk):
//   ph1: A(t+1)h0 -> buf^1 (A(t-1) dead since t-1 ph4 barrier2)
//   ph2: A(t+1)h1 -> buf^1
//   ph3: B(t+2)h0 -> buf   (B(t) fully reg-loaded at ph1)
//   ph4: B(t+2)h1 -> buf; then vmcnt(4) (lands A(t+1),B(t+1); keeps B(t+2)
//        in flight); vmcnt(0) for t>=14 (tail).
__global__ __launch_bounds__(512, 1) void gemm_qkv8(const unsigned short* __restrict__ A,
                                                    const unsigned short* __restrict__ wt,
                                                    unsigned short* __restrict__ Qb,
                                                    unsigned short* __restrict__ Kb,
                                                    unsigned short* __restrict__ Vtb,
                                                    float qscale) {
  constexpr int K = 1024;
  extern __shared__ unsigned short lds[];
  int flat = blockIdx.x;
  int xcd = flat & 7, idx = flat >> 3;   // idx 0..47
  int bm = xcd * 4 + (idx & 3);          // 0..31 (per-XCD A chunk = 2MB, L2-resident)
  int bn = idx >> 2;                     // 0..11
  int which = bn >> 2, bnl = bn & 3;
  int tid = threadIdx.x, lane = tid & 63, w = tid >> 6;
  int wm = w >> 2, wn = w & 3;
  int q = lane & 15, g = lane >> 4;
  f32x4 acc[8][4] = {};

  const unsigned short* Arow = A + (size_t)(bm * 256) * K;
  const unsigned short* Brow = wt + (size_t)which * 1048576 + (size_t)(bnl * 256) * K;

  auto STG = [&](unsigned short* dstTile, const unsigned short* src, int h, int k0) {
#pragma unroll
    for (int i = 0; i < 2; ++i) {
      int ci = w * 2 + i;                       // 0..15
      int r = h * 128 + ci * 8 + (lane >> 3);   // tile row 0..255
      gload16(src + (size_t)r * K + k0 + (((lane & 7) ^ (r & 7)) * 8),
              dstTile + h * 8192 + ci * 512);
    }
  };

  unsigned short* Ab0 = lds;
  unsigned short* Ab1 = lds + 16384;
  unsigned short* Bb0 = lds + 32768;
  unsigned short* Bb1 = lds + 49152;

  // prologue: tiles 0,1 (order matters for oldest-first vmcnt drain)
  STG(Ab0, Arow, 0, 0);  STG(Ab0, Arow, 1, 0);
  STG(Bb0, Brow, 0, 0);  STG(Bb0, Brow, 1, 0);
  STG(Ab1, Arow, 0, 64); STG(Ab1, Arow, 1, 64);
  STG(Bb1, Brow, 0, 64); STG(Bb1, Brow, 1, 64);
  asm volatile("s_waitcnt vmcnt(8)" ::: "memory");  // tile0 landed; tile1 in flight
  __builtin_amdgcn_s_barrier();

  short8 bfr[4][2];
  for (int t = 0; t < 16; ++t) {
    unsigned short* Ac = (t & 1) ? Ab1 : Ab0;
    unsigned short* Ao = (t & 1) ? Ab0 : Ab1;
    unsigned short* Bc = (t & 1) ? Bb1 : Bb0;

#define QPHASE(qd)                                                                       \
    {                                                                                    \
      short8 af[2][2];                                                                   \
      _Pragma("unroll") for (int mi = 0; mi < 2; ++mi)                                   \
        _Pragma("unroll") for (int kk = 0; kk < 2; ++kk) {                               \
          int lr = wm * 128 + (2 * (qd) + mi) * 16 + q;                                  \
          af[mi][kk] = *(const short8*)(&Ac[lr * 64 + (((kk * 4 + g) ^ (lr & 7)) * 8)]); \
        }                                                                                \
      if ((qd) == 0) {                                                                   \
        _Pragma("unroll") for (int n = 0; n < 4; ++n)                                    \
          _Pragma("unroll") for (int kk = 0; kk < 2; ++kk) {                             \
            int lrb = wn * 64 + n * 16 + q;                                              \
            bfr[n][kk] = *(const short8*)(&Bc[lrb * 64 + (((kk * 4 + g) ^ (lrb & 7)) * 8)]); \
          }                                                                              \
      }                                                                                  \
      if ((qd) == 0 && t >= 1 && t + 1 < 16) STG(Ao, Arow, 0, (t + 1) * 64);             \
      if ((qd) == 1 && t >= 1 && t + 1 < 16) STG(Ao, Arow, 1, (t + 1) * 64);             \
      if ((qd) == 2 && t + 2 < 16) STG(Bc, Brow, 0, (t + 2) * 64);                       \
      if ((qd) == 3 && t + 2 < 16) STG(Bc, Brow, 1, (t + 2) * 64);                       \
      if ((qd) == 3) {                                                                   \
        if (t >= 14) { asm volatile("s_waitcnt vmcnt(0)" ::: "memory"); }                \
        else         { asm volatile("s_waitcnt vmcnt(4)" ::: "memory"); }                \
      }                                                                                  \
      __builtin_amdgcn_s_barrier();                                                      \
      asm volatile("s_waitcnt lgkmcnt(0)" ::: "memory");                                 \
      __builtin_amdgcn_sched_barrier(0);                                                 \
      __builtin_amdgcn_s_setprio(1);                                                     \
      _Pragma("unroll") for (int mi = 0; mi < 2; ++mi)                                   \
        _Pragma("unroll") for (int n = 0; n < 4; ++n)                                    \
          _Pragma("unroll") for (int kk = 0; kk < 2; ++kk)                               \
            acc[2 * (qd) + mi][n] = __builtin_amdgcn_mfma_f32_16x16x32_bf16(             \
                af[mi][kk], bfr[n][kk], acc[2 * (qd) + mi][n], 0, 0, 0);                 \
      __builtin_amdgcn_s_setprio(0);                                                     \
      __builtin_amdgcn_s_barrier();                                                      \
    }
    QPHASE(0)
    QPHASE(1)
    QPHASE(2)
    QPHASE(3)
#undef QPHASE
  }

  int rbase = bm * 256 + wm * 128;
  int cb = bnl * 256 + wn * 64;
#pragma unroll
  for (int m = 0; m < 8; ++m)
#pragma unroll
    for (int n = 0; n < 4; ++n) {
      int row0 = rbase + m * 16 + g * 4;
      int col = cb + n * 16 + q;
      int h = col >> 6, d = col & 63;
      int b = row0 >> 12, s0 = row0 & 4095;
      if (which == 0) {
#pragma unroll
        for (int reg = 0; reg < 4; ++reg)
          Qb[((size_t)(b * 16 + h) * 4096 + s0 + reg) * 64 + d] = f2bf(acc[m][n][reg] * qscale);
      } else if (which == 1) {
#pragma unroll
        for (int reg = 0; reg < 4; ++reg)
          Kb[((size_t)(b * 16 + h) * 4096 + s0 + reg) * 64 + d] = f2bf(acc[m][n][reg]);
      } else {
        u32x2 pk;
        asm("v_cvt_pk_bf16_f32 %0, %1, %2" : "=v"(pk[0]) : "v"(acc[m][n][0]), "v"(acc[m][n][1]));
        asm("v_cvt_pk_bf16_f32 %0, %1, %2" : "=v"(pk[1]) : "v"(acc[m][n][2]), "v"(acc[m][n][3]));
        *(u32x2*)(Vtb + ((((size_t)(b * 16 + h) * 64 + (s0 >> 6)) * 64 + d) * 64 + (s0 & 63))) = pk;
      }
    }
}

// ---------------- output GEMM: f32 out (R12/R15 proven 2-phase) ----------------
__global__ __launch_bounds__(256, 2) void gemm_out(const unsigned short* __restrict__ A,
                                                   const unsigned short* __restrict__ Bt,
                                                   float* __restrict__ dst) {
  constexpr int K = 1024;
  __shared__ __align__(16) unsigned short As[2][128 * 64];
  __shared__ __align__(16) unsigned short Bs[2][128 * 64];
  int flat = blockIdx.x + 8 * blockIdx.y;
  int xcd = flat & 7, idx = flat >> 3;
  int bm = xcd * 8 + (idx & 7);
  int bn = idx >> 3;
  int tid = threadIdx.x, lane = tid & 63, w = tid >> 6;
  int wr = w >> 1, wc = w & 1;
  f32x4 acc[4][4] = {};

  int sr[4], soff[4];
#pragma unroll
  for (int i = 0; i < 4; ++i) {
    int ci = w * 4 + i;
    int r = ci * 8 + (lane >> 3);
    sr[i] = r;
    soff[i] = ((lane & 7) ^ (r & 7)) * 8;
  }
  const unsigned short* Arow = A + (size_t)(bm * 128) * K;
  const unsigned short* Brow = Bt + (size_t)(bn * 128) * K;

  auto STAGE = [&](int bi, int k0) {
#pragma unroll
    for (int i = 0; i < 4; ++i) {
      gload16(Arow + (size_t)sr[i] * K + k0 + soff[i], &As[bi][(w * 4 + i) * 512]);
      gload16(Brow + (size_t)sr[i] * K + k0 + soff[i], &Bs[bi][(w * 4 + i) * 512]);
    }
  };

  STAGE(0, 0);
  for (int kt = 0; kt < 16; ++kt) {
    int cur = kt & 1;
    if (kt < 15) {
      STAGE(cur ^ 1, (kt + 1) * 64);
      asm volatile("s_waitcnt vmcnt(8)" ::: "memory");
    } else {
      asm volatile("s_waitcnt vmcnt(0)" ::: "memory");
    }
    __builtin_amdgcn_s_barrier();
    __builtin_amdgcn_sched_barrier(0);
    short8 af[2][4], bfr[2][4];
#pragma unroll
    for (int c = 0; c < 2; ++c) {
#pragma unroll
      for (int m = 0; m < 4; ++m) {
        int cc = (lane >> 4) + 4 * c;
        int ra = wr * 64 + m * 16 + (lane & 15);
        af[c][m] = *(const short8*)(&As[cur][ra * 64 + ((cc ^ (ra & 7)) * 8)]);
        int rb = wc * 64 + m * 16 + (lane & 15);
        bfr[c][m] = *(const short8*)(&Bs[cur][rb * 64 + ((cc ^ (rb & 7)) * 8)]);
      }
    }
#pragma unroll
    for (int c = 0; c < 2; ++c)
#pragma unroll
      for (int m = 0; m < 4; ++m)
#pragma unroll
        for (int n = 0; n < 4; ++n)
          acc[m][n] = __builtin_amdgcn_mfma_f32_16x16x32_bf16(af[c][m], bfr[c][n], acc[m][n], 0, 0, 0);
    __builtin_amdgcn_s_barrier();
    __builtin_amdgcn_sched_barrier(0);
  }

  int rbase = bm * 128 + wr * 64;
  int cbase = bn * 128 + wc * 64;
#pragma unroll
  for (int m = 0; m < 4; ++m)
#pragma unroll
    for (int n = 0; n < 4; ++n) {
      int row0 = rbase + m * 16 + (lane >> 4) * 4;
      int col = cbase + n * 16 + (lane & 15);
#pragma unroll
      for (int reg = 0; reg < 4; ++reg)
        dst[(size_t)(row0 + reg) * 1024 + col] = acc[m][n][reg];
    }
}

// ---------------- sparse attention (unchanged from R15/R16) ----------------
__global__ __launch_bounds__(256) void attn_kernel(const unsigned short* __restrict__ Qh,
                            const unsigned short* __restrict__ Kh,
                            const unsigned short* __restrict__ Vbt,
                            const int* __restrict__ bidx,
                            unsigned short* __restrict__ attn_out,
                            float* __restrict__ Opart,
                            float* __restrict__ lpart) {
  __shared__ __align__(16) unsigned short Ks[3][64 * 64];
  __shared__ __align__(16) unsigned short Vs[2][64 * 64];
  int flat = blockIdx.x + 71 * blockIdx.y;
  int nf = (flat & 7) * 284 + (flat >> 3);
  int gx = nf % 71, bh = nf / 71;
  int h = bh & 15;
  int tid = threadIdx.x, lane = tid & 63, w = tid >> 6;
  int q = lane & 15, g = lane >> 4;
  float slope2 = exp2f(-0.5f * (float)(h + 1)) * 1.44269504f;

  int qb, nkb;
  int vlist;
  if (gx < 63) {
    qb = gx + 1;
    int v = -1;
    if (lane == 0) v = 0;
    else if (lane <= 12) v = bidx[qb * 12 + (lane - 1)];
    vlist = v;
    unsigned long long msk = __ballot(v >= 0);
    nkb = __builtin_popcountll(msk & 0x1FFFull);
  } else {
    qb = 0;
    nkb = 8;
    vlist = (gx - 63) * 8 + lane;
  }

  int qrow = qb * 64 + w * 16 + q;
  const unsigned short* qptr = Qh + ((size_t)bh * 4096 + qrow) * 64 + g * 8;
  short8 qf0 = *(const short8*)qptr;
  short8 qf1 = *(const short8*)(qptr + 32);

  float qposf = (float)qrow;
  float sq = slope2 * qposf;
  float er[4][4];
#pragma unroll
  for (int ct = 0; ct < 4; ++ct)
#pragma unroll
    for (int r = 0; r < 4; ++r) er[ct][r] = slope2 * (float)(ct * 16 + r);

  float psum = 0.f;
  f32x4 accO[4] = {};

  const unsigned short* Kbh = Kh + (size_t)bh * 4096 * 64;
  const unsigned short* Vbh = Vbt + (size_t)bh * 4096 * 64;

  int srr[2], so[2];
#pragma unroll
  for (int i = 0; i < 2; ++i) {
    int ci = w * 2 + i;
    int r = ci * 8 + (lane >> 3);
    srr[i] = r;
    so[i] = ((lane & 7) ^ (r & 7)) * 8;
  }
  auto STAGE_K = [&](int bi, int kb) {
    const unsigned short* kbase = Kbh + (size_t)kb * 4096;
#pragma unroll
    for (int i = 0; i < 2; ++i)
      gload16(kbase + srr[i] * 64 + so[i], &Ks[bi][(w * 2 + i) * 512]);
  };
  auto STAGE_V = [&](int bi, int kb) {
    const unsigned short* vbase = Vbh + (size_t)kb * 4096;
#pragma unroll
    for (int i = 0; i < 2; ++i)
      gload16(vbase + srr[i] * 64 + so[i], &Vs[bi][(w * 2 + i) * 512]);
  };

  STAGE_K(0, __builtin_amdgcn_readlane(vlist, 0));
  STAGE_V(0, __builtin_amdgcn_readlane(vlist, 0));
  STAGE_K(1, __builtin_amdgcn_readlane(vlist, 1));

  for (int it = 0; it < nkb; ++it) {
    int curK = it % 3, curV = it & 1;
    int kb = __builtin_amdgcn_readlane(vlist, it);
    if (it + 1 < nkb) {
      asm volatile("s_waitcnt vmcnt(2)" ::: "memory");
    } else {
      asm volatile("s_waitcnt vmcnt(0)" ::: "memory");
    }
    __builtin_amdgcn_s_barrier();
    __builtin_amdgcn_sched_barrier(0);
    if (it + 1 < nkb) STAGE_V((it + 1) & 1, __builtin_amdgcn_readlane(vlist, it + 1));
    if (it + 2 < nkb) STAGE_K((it + 2) % 3, __builtin_amdgcn_readlane(vlist, it + 2));

    float kb4g = (float)(kb * 64 + 4 * g);
    float d_[4][4];
    if (kb != qb) {
      if (kb < qb) {
        float t = __builtin_fmaf(slope2, kb4g, -sq);
#pragma unroll
        for (int ct = 0; ct < 4; ++ct)
#pragma unroll
          for (int r = 0; r < 4; ++r) d_[ct][r] = t + er[ct][r];
      } else {
        float t = sq - slope2 * kb4g;
#pragma unroll
        for (int ct = 0; ct < 4; ++ct)
#pragma unroll
          for (int r = 0; r < 4; ++r) d_[ct][r] = t - er[ct][r];
      }
    } else {
      float db = qposf - kb4g;
#pragma unroll
      for (int ct = 0; ct < 4; ++ct)
#pragma unroll
        for (int r = 0; r < 4; ++r)
          d_[ct][r] = -slope2 * fabsf(db - (float)(ct * 16 + r));
    }

    float pv[4][4];
    __builtin_amdgcn_s_setprio(1);
#pragma unroll
    for (int ct = 0; ct < 4; ++ct) {
      int kr = ct * 16 + q;
      short8 kf0 = *(const short8*)(&Ks[curK][kr * 64 + ((g ^ (kr & 7)) * 8)]);
      short8 kf1 = *(const short8*)(&Ks[curK][kr * 64 + (((g + 4) ^ (kr & 7)) * 8)]);
      f32x4 cin = {d_[ct][0], d_[ct][1], d_[ct][2], d_[ct][3]};
      f32x4 s = __builtin_amdgcn_mfma_f32_16x16x32_bf16(kf0, qf0, cin, 0, 0, 0);
      s = __builtin_amdgcn_mfma_f32_16x16x32_bf16(kf1, qf1, s, 0, 0, 0);
#pragma unroll
      for (int r = 0; r < 4; ++r) {
        float p = exp2f(s[r]);
        pv[ct][r] = p;
        psum += p;
      }
    }
    __builtin_amdgcn_s_setprio(0);

    uint32_t pkw[4][2];
#pragma unroll
    for (int ct = 0; ct < 4; ++ct) {
      asm("v_cvt_pk_bf16_f32 %0, %1, %2" : "=v"(pkw[ct][0]) : "v"(pv[ct][0]), "v"(pv[ct][1]));
      asm("v_cvt_pk_bf16_f32 %0, %1, %2" : "=v"(pkw[ct][1]) : "v"(pv[ct][2]), "v"(pv[ct][3]));
    }
    bool odd = (tid & 16) != 0;
    short8 pa[2];
#pragma unroll
    for (int f = 0; f < 2; ++f) {
      uint32_t s0 = pkw[2 * f][0], s1 = pkw[2 * f][1];
      uint32_t t0 = pkw[2 * f + 1][0], t1 = pkw[2 * f + 1][1];
      asm("v_permlane32_swap_b32 %0, %1" : "+v"(s0), "+v"(t0));
      asm("v_permlane32_swap_b32 %0, %1" : "+v"(s1), "+v"(t1));
      uint32_t xs0 = (uint32_t)__shfl_xor((int)s0, 16, 64);
      uint32_t xs1 = (uint32_t)__shfl_xor((int)s1, 16, 64);
      uint32_t xt0 = (uint32_t)__shfl_xor((int)t0, 16, 64);
      uint32_t xt1 = (uint32_t)__shfl_xor((int)t1, 16, 64);
      union { uint32_t w[4]; short8 v; } u;
      u.w[0] = odd ? xt0 : s0;
      u.w[1] = odd ? xt1 : s1;
      u.w[2] = odd ? t0 : xs0;
      u.w[3] = odd ? t1 : xs1;
      pa[f] = u.v;
    }

    __builtin_amdgcn_s_setprio(1);
#pragma unroll
    for (int dt = 0; dt < 4; ++dt) {
      int dr = dt * 16 + q;
      short8 vf0 = *(const short8*)(&Vs[curV][dr * 64 + ((g ^ (dr & 7)) * 8)]);
      short8 vf1 = *(const short8*)(&Vs[curV][dr * 64 + (((g + 4) ^ (dr & 7)) * 8)]);
      accO[dt] = __builtin_amdgcn_mfma_f32_16x16x32_bf16(pa[0], vf0, accO[dt], 0, 0, 0);
      accO[dt] = __builtin_amdgcn_mfma_f32_16x16x32_bf16(pa[1], vf1, accO[dt], 0, 0, 0);
    }
    __builtin_amdgcn_s_setprio(0);
  }

  float lt = psum;
  lt += __shfl_xor(lt, 16, 64);
  lt += __shfl_xor(lt, 32, 64);

  int b = bh >> 4;
  if (gx < 63) {
#pragma unroll
    for (int reg = 0; reg < 4; ++reg) {
      float ls = __shfl(lt, 4 * g + reg, 64);
      float rl = 1.0f / ls;
      int row = qb * 64 + w * 16 + 4 * g + reg;
#pragma unroll
      for (int dt = 0; dt < 4; ++dt) {
        int col = h * 64 + dt * 16 + q;
        attn_out[((size_t)b * 4096 + row) * 1024 + col] = f2bf(accO[dt][reg] * rl);
      }
    }
  } else {
    int chunk = gx - 63;
    float* Op = Opart + (size_t)(bh * 8 + chunk) * 64 * 64;
    float* lp = lpart + (size_t)(bh * 8 + chunk) * 64;
#pragma unroll
    for (int reg = 0; reg < 4; ++reg) {
      int row = w * 16 + 4 * g + reg;
#pragma unroll
      for (int dt = 0; dt < 4; ++dt) {
        int col = dt * 16 + q;
        Op[row * 64 + col] = accO[dt][reg];
      }
    }
    if (g == 0) lp[w * 16 + q] = lt;
  }
}

// ---------------- merge the 8 qb=0 chunks ----------------
__global__ void merge_qb0(const float* __restrict__ Opart, const float* __restrict__ lpart,
                          unsigned short* __restrict__ attn_out) {
  int bh = blockIdx.x;
  int tid = threadIdx.x;
  int row = tid >> 2, cg = tid & 3;
  const float* lp = lpart + (size_t)bh * 8 * 64;
  float L = 0.f;
#pragma unroll
  for (int c = 0; c < 8; ++c) L += lp[c * 64 + row];
  float rL = 1.0f / L;
  int b = bh >> 4, h = bh & 15;
  f32x4 acc0 = {}, acc1 = {}, acc2 = {}, acc3 = {};
#pragma unroll
  for (int c = 0; c < 8; ++c) {
    const float* Op = Opart + ((size_t)(bh * 8 + c) * 64 + row) * 64 + cg * 16;
    acc0 += ((const f32x4*)Op)[0];
    acc1 += ((const f32x4*)Op)[1];
    acc2 += ((const f32x4*)Op)[2];
    acc3 += ((const f32x4*)Op)[3];
  }
  unsigned short* out = attn_out + ((size_t)b * 4096 + row) * 1024 + h * 64 + cg * 16;
#pragma unroll
  for (int j = 0; j < 4; ++j) {
    out[j] = f2bf(acc0[j] * rL);
    out[4 + j] = f2bf(acc1[j] * rL);
    out[8 + j] = f2bf(acc2[j] * rL);
    out[12 + j] = f2bf(acc3[j] * rL);
  }
}

extern "C" void kernel_launch(void* const* d_in, const int* in_sizes, int n_in,
                              void* d_out, int out_size, void* d_ws, size_t ws_size,
                              hipStream_t stream) {
  const float* x = (const float*)d_in[0];
  const float* Wq = (const float*)d_in[1];
  const float* Wk = (const float*)d_in[2];
  const float* Wv = (const float*)d_in[3];
  const float* Wo = (const float*)d_in[4];
  const int* bidx = (const int*)d_in[5];

  char* ws = (char*)d_ws;
  unsigned short* xb = (unsigned short*)(ws);
  unsigned short* wt = (unsigned short*)(ws + 16777216);
  unsigned short* Qb = (unsigned short*)(ws + 25165824);
  unsigned short* Kb = (unsigned short*)(ws + 41943040);
  unsigned short* Vtb = (unsigned short*)(ws + 58720256);
  unsigned short* attnb = (unsigned short*)(ws + 75497472);
  float* Opart = (float*)(ws);
  float* lpart = (float*)(ws + 4194304);

  // allow 128KB dynamic LDS for the 256^2 GEMM (idempotent, deterministic)
  hipFuncSetAttribute((const void*)gemm_qkv8,
                      hipFuncAttributeMaxDynamicSharedMemorySize, 131072);

  prep_kernel<<<5120, 256, 0, stream>>>(x, xb, Wq, Wk, Wv, Wo, wt);
  gemm_qkv8<<<384, 512, 131072, stream>>>(xb, wt, Qb, Kb, Vtb, 0.18033688f);
  attn_kernel<<<dim3(71, 32), 256, 0, stream>>>(Qb, Kb, Vtb, bidx, attnb, Opart, lpart);
  merge_qb0<<<32, 256, 0, stream>>>(Opart, lpart, attnb);
  gemm_out<<<dim3(8, 64), 256, 0, stream>>>(attnb, wt + 3145728, (float*)d_out);
}

// Round 18
// 163.955 us; speedup vs baseline: 1.0713x; 1.0713x over previous
//
#include <hip/hip_runtime.h>
#include <stdint.h>

typedef __attribute__((ext_vector_type(8))) short short8;
typedef __attribute__((ext_vector_type(4))) float f32x4;
typedef __attribute__((ext_vector_type(8))) unsigned short u16x8;
typedef __attribute__((ext_vector_type(2))) unsigned int u32x2;

#define DEV static __device__ __forceinline__

DEV unsigned short f2bf(float f) {
  union { float f; uint32_t u; } v; v.f = f;
  uint32_t r = v.u + 0x7FFFu + ((v.u >> 16) & 1u);
  return (unsigned short)(r >> 16);
}

DEV void gload16(const void* g, void* l) {
  __builtin_amdgcn_global_load_lds(
      (const __attribute__((address_space(1))) void*)g,
      (__attribute__((address_space(3))) void*)l, 16, 0, 0);
}

// ---------------- fused prep: cast x (blocks 0..4095) + transpose W (4096..5119) ----
__global__ __launch_bounds__(256) void prep_kernel(const float* __restrict__ x,
                                                   unsigned short* __restrict__ xb,
                                                   const float* __restrict__ Wq,
                                                   const float* __restrict__ Wk,
                                                   const float* __restrict__ Wv,
                                                   const float* __restrict__ Wo,
                                                   unsigned short* __restrict__ wt) {
  __shared__ float tile[64][65];
  int t = threadIdx.x;
  if (blockIdx.x < 4096) {
    int i = blockIdx.x * 256 + t;
    f32x4 a = ((const f32x4*)x)[2 * i];
    f32x4 b = ((const f32x4*)x)[2 * i + 1];
    u16x8 o;
    o[0] = f2bf(a[0]); o[1] = f2bf(a[1]); o[2] = f2bf(a[2]); o[3] = f2bf(a[3]);
    o[4] = f2bf(b[0]); o[5] = f2bf(b[1]); o[6] = f2bf(b[2]); o[7] = f2bf(b[3]);
    ((u16x8*)xb)[i] = o;
    return;
  }
  int flat = blockIdx.x - 4096;
  int bn = flat & 15, bk = (flat >> 4) & 15, z = flat >> 8;
  const float* W = (z == 0) ? Wq : (z == 1) ? Wk : (z == 2) ? Wv : Wo;
  unsigned short* dst = wt + (size_t)z * 1024 * 1024;
  int c = t & 63, rr = t >> 6;
#pragma unroll
  for (int p = 0; p < 16; ++p) {
    int r = p * 4 + rr;
    tile[r][c] = W[(size_t)(bk * 64 + r) * 1024 + bn * 64 + c];
  }
  __syncthreads();
#pragma unroll
  for (int p = 0; p < 16; ++p) {
    int r2 = p * 4 + rr;
    dst[(size_t)(bn * 64 + r2) * 1024 + bk * 64 + c] = f2bf(tile[c][r2]);
  }
}

// ---------------- fused QKV GEMM (proven R12/R15 2-phase, counted vmcnt) ----------------
__global__ __launch_bounds__(256, 2) void gemm_qkv(const unsigned short* __restrict__ A,
                                                   const unsigned short* __restrict__ wt,
                                                   unsigned short* __restrict__ Qb,
                                                   unsigned short* __restrict__ Kb,
                                                   unsigned short* __restrict__ Vtb,
                                                   float qscale) {
  constexpr int K = 1024;
  __shared__ __align__(16) unsigned short As[2][128 * 64];
  __shared__ __align__(16) unsigned short Bs[2][128 * 64];
  int flat = blockIdx.x + 24 * blockIdx.y;
  int xcd = flat & 7, idx = flat >> 3;      // idx 0..191
  int bm = xcd * 8 + (idx & 7);             // per-XCD M-chunk (A L2-resident)
  int bn = idx >> 3;                        // 0..23
  int which = bn >> 3, bnn = bn & 7;
  int tid = threadIdx.x, lane = tid & 63, w = tid >> 6;
  int wr = w >> 1, wc = w & 1;
  f32x4 acc[4][4] = {};

  int sr[4], soff[4];
#pragma unroll
  for (int i = 0; i < 4; ++i) {
    int ci = w * 4 + i;
    int r = ci * 8 + (lane >> 3);
    sr[i] = r;
    soff[i] = ((lane & 7) ^ (r & 7)) * 8;
  }
  const unsigned short* Arow = A + (size_t)(bm * 128) * K;
  const unsigned short* Brow = wt + (size_t)which * 1048576 + (size_t)(bnn * 128) * K;

  auto STAGE = [&](int bi, int k0) {
#pragma unroll
    for (int i = 0; i < 4; ++i) {
      gload16(Arow + (size_t)sr[i] * K + k0 + soff[i], &As[bi][(w * 4 + i) * 512]);
      gload16(Brow + (size_t)sr[i] * K + k0 + soff[i], &Bs[bi][(w * 4 + i) * 512]);
    }
  };

  STAGE(0, 0);
  for (int kt = 0; kt < 16; ++kt) {
    int cur = kt & 1;
    if (kt < 15) {
      STAGE(cur ^ 1, (kt + 1) * 64);
      asm volatile("s_waitcnt vmcnt(8)" ::: "memory");
    } else {
      asm volatile("s_waitcnt vmcnt(0)" ::: "memory");
    }
    __builtin_amdgcn_s_barrier();
    __builtin_amdgcn_sched_barrier(0);
    short8 af[2][4], bfr[2][4];
#pragma unroll
    for (int c = 0; c < 2; ++c) {
#pragma unroll
      for (int m = 0; m < 4; ++m) {
        int cc = (lane >> 4) + 4 * c;
        int ra = wr * 64 + m * 16 + (lane & 15);
        af[c][m] = *(const short8*)(&As[cur][ra * 64 + ((cc ^ (ra & 7)) * 8)]);
        int rb = wc * 64 + m * 16 + (lane & 15);
        bfr[c][m] = *(const short8*)(&Bs[cur][rb * 64 + ((cc ^ (rb & 7)) * 8)]);
      }
    }
#pragma unroll
    for (int c = 0; c < 2; ++c)
#pragma unroll
      for (int m = 0; m < 4; ++m)
#pragma unroll
        for (int n = 0; n < 4; ++n)
          acc[m][n] = __builtin_amdgcn_mfma_f32_16x16x32_bf16(af[c][m], bfr[c][n], acc[m][n], 0, 0, 0);
    __builtin_amdgcn_s_barrier();
    __builtin_amdgcn_sched_barrier(0);
  }

  int rbase = bm * 128 + wr * 64;
  int cbase = bnn * 128 + wc * 64;
#pragma unroll
  for (int m = 0; m < 4; ++m)
#pragma unroll
    for (int n = 0; n < 4; ++n) {
      int row0 = rbase + m * 16 + (lane >> 4) * 4;
      int col = cbase + n * 16 + (lane & 15);
      int h = col >> 6, d = col & 63;
      int b = row0 >> 12, s0 = row0 & 4095;
      if (which == 0) {
#pragma unroll
        for (int reg = 0; reg < 4; ++reg)
          Qb[((size_t)(b * 16 + h) * 4096 + s0 + reg) * 64 + d] = f2bf(acc[m][n][reg] * qscale);
      } else if (which == 1) {
#pragma unroll
        for (int reg = 0; reg < 4; ++reg)
          Kb[((size_t)(b * 16 + h) * 4096 + s0 + reg) * 64 + d] = f2bf(acc[m][n][reg]);
      } else {
        u32x2 pk;
        asm("v_cvt_pk_bf16_f32 %0, %1, %2" : "=v"(pk[0]) : "v"(acc[m][n][0]), "v"(acc[m][n][1]));
        asm("v_cvt_pk_bf16_f32 %0, %1, %2" : "=v"(pk[1]) : "v"(acc[m][n][2]), "v"(acc[m][n][3]));
        *(u32x2*)(Vtb + ((((size_t)(b * 16 + h) * 64 + (s0 >> 6)) * 64 + d) * 64 + (s0 & 63))) = pk;
      }
    }
}

// ---------------- output GEMM: f32 out (proven 2-phase) ----------------
__global__ __launch_bounds__(256, 2) void gemm_out(const unsigned short* __restrict__ A,
                                                   const unsigned short* __restrict__ Bt,
                                                   float* __restrict__ dst) {
  constexpr int K = 1024;
  __shared__ __align__(16) unsigned short As[2][128 * 64];
  __shared__ __align__(16) unsigned short Bs[2][128 * 64];
  int flat = blockIdx.x + 8 * blockIdx.y;
  int xcd = flat & 7, idx = flat >> 3;
  int bm = xcd * 8 + (idx & 7);
  int bn = idx >> 3;
  int tid = threadIdx.x, lane = tid & 63, w = tid >> 6;
  int wr = w >> 1, wc = w & 1;
  f32x4 acc[4][4] = {};

  int sr[4], soff[4];
#pragma unroll
  for (int i = 0; i < 4; ++i) {
    int ci = w * 4 + i;
    int r = ci * 8 + (lane >> 3);
    sr[i] = r;
    soff[i] = ((lane & 7) ^ (r & 7)) * 8;
  }
  const unsigned short* Arow = A + (size_t)(bm * 128) * K;
  const unsigned short* Brow = Bt + (size_t)(bn * 128) * K;

  auto STAGE = [&](int bi, int k0) {
#pragma unroll
    for (int i = 0; i < 4; ++i) {
      gload16(Arow + (size_t)sr[i] * K + k0 + soff[i], &As[bi][(w * 4 + i) * 512]);
      gload16(Brow + (size_t)sr[i] * K + k0 + soff[i], &Bs[bi][(w * 4 + i) * 512]);
    }
  };

  STAGE(0, 0);
  for (int kt = 0; kt < 16; ++kt) {
    int cur = kt & 1;
    if (kt < 15) {
      STAGE(cur ^ 1, (kt + 1) * 64);
      asm volatile("s_waitcnt vmcnt(8)" ::: "memory");
    } else {
      asm volatile("s_waitcnt vmcnt(0)" ::: "memory");
    }
    __builtin_amdgcn_s_barrier();
    __builtin_amdgcn_sched_barrier(0);
    short8 af[2][4], bfr[2][4];
#pragma unroll
    for (int c = 0; c < 2; ++c) {
#pragma unroll
      for (int m = 0; m < 4; ++m) {
        int cc = (lane >> 4) + 4 * c;
        int ra = wr * 64 + m * 16 + (lane & 15);
        af[c][m] = *(const short8*)(&As[cur][ra * 64 + ((cc ^ (ra & 7)) * 8)]);
        int rb = wc * 64 + m * 16 + (lane & 15);
        bfr[c][m] = *(const short8*)(&Bs[cur][rb * 64 + ((cc ^ (rb & 7)) * 8)]);
      }
    }
#pragma unroll
    for (int c = 0; c < 2; ++c)
#pragma unroll
      for (int m = 0; m < 4; ++m)
#pragma unroll
        for (int n = 0; n < 4; ++n)
          acc[m][n] = __builtin_amdgcn_mfma_f32_16x16x32_bf16(af[c][m], bfr[c][n], acc[m][n], 0, 0, 0);
    __builtin_amdgcn_s_barrier();
    __builtin_amdgcn_sched_barrier(0);
  }

  int rbase = bm * 128 + wr * 64;
  int cbase = bn * 128 + wc * 64;
#pragma unroll
  for (int m = 0; m < 4; ++m)
#pragma unroll
    for (int n = 0; n < 4; ++n) {
      int row0 = rbase + m * 16 + (lane >> 4) * 4;
      int col = cbase + n * 16 + (lane & 15);
#pragma unroll
      for (int reg = 0; reg < 4; ++reg)
        dst[(size_t)(row0 + reg) * 1024 + col] = acc[m][n][reg];
    }
}

// ---------------- sparse attention (proven R15 version) ----------------
__global__ __launch_bounds__(256) void attn_kernel(const unsigned short* __restrict__ Qh,
                            const unsigned short* __restrict__ Kh,
                            const unsigned short* __restrict__ Vbt,
                            const int* __restrict__ bidx,
                            unsigned short* __restrict__ attn_out,
                            float* __restrict__ Opart,
                            float* __restrict__ lpart) {
  __shared__ __align__(16) unsigned short Ks[3][64 * 64];
  __shared__ __align__(16) unsigned short Vs[2][64 * 64];
  int flat = blockIdx.x + 71 * blockIdx.y;
  int nf = (flat & 7) * 284 + (flat >> 3);  // bijective chunked XCD swizzle
  int gx = nf % 71, bh = nf / 71;
  int h = bh & 15;
  int tid = threadIdx.x, lane = tid & 63, w = tid >> 6;
  int q = lane & 15, g = lane >> 4;
  float slope2 = exp2f(-0.5f * (float)(h + 1)) * 1.44269504f;

  int qb, nkb;
  int vlist;
  if (gx < 63) {
    qb = gx + 1;
    int v = -1;
    if (lane == 0) v = 0;
    else if (lane <= 12) v = bidx[qb * 12 + (lane - 1)];
    vlist = v;
    unsigned long long msk = __ballot(v >= 0);
    nkb = __builtin_popcountll(msk & 0x1FFFull);
  } else {
    qb = 0;
    nkb = 8;
    vlist = (gx - 63) * 8 + lane;
  }

  int qrow = qb * 64 + w * 16 + q;
  const unsigned short* qptr = Qh + ((size_t)bh * 4096 + qrow) * 64 + g * 8;
  short8 qf0 = *(const short8*)qptr;
  short8 qf1 = *(const short8*)(qptr + 32);

  float qposf = (float)qrow;
  float sq = slope2 * qposf;
  float er[4][4];
#pragma unroll
  for (int ct = 0; ct < 4; ++ct)
#pragma unroll
    for (int r = 0; r < 4; ++r) er[ct][r] = slope2 * (float)(ct * 16 + r);

  float psum = 0.f;
  f32x4 accO[4] = {};

  const unsigned short* Kbh = Kh + (size_t)bh * 4096 * 64;
  const unsigned short* Vbh = Vbt + (size_t)bh * 4096 * 64;

  int srr[2], so[2];
#pragma unroll
  for (int i = 0; i < 2; ++i) {
    int ci = w * 2 + i;
    int r = ci * 8 + (lane >> 3);
    srr[i] = r;
    so[i] = ((lane & 7) ^ (r & 7)) * 8;
  }
  auto STAGE_K = [&](int bi, int kb) {
    const unsigned short* kbase = Kbh + (size_t)kb * 4096;
#pragma unroll
    for (int i = 0; i < 2; ++i)
      gload16(kbase + srr[i] * 64 + so[i], &Ks[bi][(w * 2 + i) * 512]);
  };
  auto STAGE_V = [&](int bi, int kb) {
    const unsigned short* vbase = Vbh + (size_t)kb * 4096;
#pragma unroll
    for (int i = 0; i < 2; ++i)
      gload16(vbase + srr[i] * 64 + so[i], &Vs[bi][(w * 2 + i) * 512]);
  };

  // prologue: K0, V0, K1 (oldest-first drain leaves K1 in flight at iter 0)
  STAGE_K(0, __builtin_amdgcn_readlane(vlist, 0));
  STAGE_V(0, __builtin_amdgcn_readlane(vlist, 0));
  STAGE_K(1, __builtin_amdgcn_readlane(vlist, 1));

  for (int it = 0; it < nkb; ++it) {
    int curK = it % 3, curV = it & 1;
    int kb = __builtin_amdgcn_readlane(vlist, it);
    if (it + 1 < nkb) {
      asm volatile("s_waitcnt vmcnt(2)" ::: "memory");
    } else {
      asm volatile("s_waitcnt vmcnt(0)" ::: "memory");
    }
    __builtin_amdgcn_s_barrier();
    __builtin_amdgcn_sched_barrier(0);
    if (it + 1 < nkb) STAGE_V((it + 1) & 1, __builtin_amdgcn_readlane(vlist, it + 1));
    if (it + 2 < nkb) STAGE_K((it + 2) % 3, __builtin_amdgcn_readlane(vlist, it + 2));

    float kb4g = (float)(kb * 64 + 4 * g);
    float d_[4][4];
    if (kb != qb) {
      if (kb < qb) {
        float t = __builtin_fmaf(slope2, kb4g, -sq);
#pragma unroll
        for (int ct = 0; ct < 4; ++ct)
#pragma unroll
          for (int r = 0; r < 4; ++r) d_[ct][r] = t + er[ct][r];
      } else {
        float t = sq - slope2 * kb4g;
#pragma unroll
        for (int ct = 0; ct < 4; ++ct)
#pragma unroll
          for (int r = 0; r < 4; ++r) d_[ct][r] = t - er[ct][r];
      }
    } else {
      float db = qposf - kb4g;
#pragma unroll
      for (int ct = 0; ct < 4; ++ct)
#pragma unroll
        for (int r = 0; r < 4; ++r)
          d_[ct][r] = -slope2 * fabsf(db - (float)(ct * 16 + r));
    }

    float pv[4][4];
    __builtin_amdgcn_s_setprio(1);
#pragma unroll
    for (int ct = 0; ct < 4; ++ct) {
      int kr = ct * 16 + q;
      short8 kf0 = *(const short8*)(&Ks[curK][kr * 64 + ((g ^ (kr & 7)) * 8)]);
      short8 kf1 = *(const short8*)(&Ks[curK][kr * 64 + (((g + 4) ^ (kr & 7)) * 8)]);
      f32x4 cin = {d_[ct][0], d_[ct][1], d_[ct][2], d_[ct][3]};
      f32x4 s = __builtin_amdgcn_mfma_f32_16x16x32_bf16(kf0, qf0, cin, 0, 0, 0);
      s = __builtin_amdgcn_mfma_f32_16x16x32_bf16(kf1, qf1, s, 0, 0, 0);
#pragma unroll
      for (int r = 0; r < 4; ++r) {
        float p = exp2f(s[r]);
        pv[ct][r] = p;
        psum += p;
      }
    }
    __builtin_amdgcn_s_setprio(0);

    // in-register P^T -> PV A-fragment redistribution (T12)
    uint32_t pkw[4][2];
#pragma unroll
    for (int ct = 0; ct < 4; ++ct) {
      asm("v_cvt_pk_bf16_f32 %0, %1, %2" : "=v"(pkw[ct][0]) : "v"(pv[ct][0]), "v"(pv[ct][1]));
      asm("v_cvt_pk_bf16_f32 %0, %1, %2" : "=v"(pkw[ct][1]) : "v"(pv[ct][2]), "v"(pv[ct][3]));
    }
    bool odd = (tid & 16) != 0;
    short8 pa[2];
#pragma unroll
    for (int f = 0; f < 2; ++f) {
      uint32_t s0 = pkw[2 * f][0], s1 = pkw[2 * f][1];
      uint32_t t0 = pkw[2 * f + 1][0], t1 = pkw[2 * f + 1][1];
      asm("v_permlane32_swap_b32 %0, %1" : "+v"(s0), "+v"(t0));
      asm("v_permlane32_swap_b32 %0, %1" : "+v"(s1), "+v"(t1));
      uint32_t xs0 = (uint32_t)__shfl_xor((int)s0, 16, 64);
      uint32_t xs1 = (uint32_t)__shfl_xor((int)s1, 16, 64);
      uint32_t xt0 = (uint32_t)__shfl_xor((int)t0, 16, 64);
      uint32_t xt1 = (uint32_t)__shfl_xor((int)t1, 16, 64);
      union { uint32_t w[4]; short8 v; } u;
      u.w[0] = odd ? xt0 : s0;
      u.w[1] = odd ? xt1 : s1;
      u.w[2] = odd ? t0 : xs0;
      u.w[3] = odd ? t1 : xs1;
      pa[f] = u.v;
    }

    __builtin_amdgcn_s_setprio(1);
#pragma unroll
    for (int dt = 0; dt < 4; ++dt) {
      int dr = dt * 16 + q;
      short8 vf0 = *(const short8*)(&Vs[curV][dr * 64 + ((g ^ (dr & 7)) * 8)]);
      short8 vf1 = *(const short8*)(&Vs[curV][dr * 64 + (((g + 4) ^ (dr & 7)) * 8)]);
      accO[dt] = __builtin_amdgcn_mfma_f32_16x16x32_bf16(pa[0], vf0, accO[dt], 0, 0, 0);
      accO[dt] = __builtin_amdgcn_mfma_f32_16x16x32_bf16(pa[1], vf1, accO[dt], 0, 0, 0);
    }
    __builtin_amdgcn_s_setprio(0);
  }

  float lt = psum;
  lt += __shfl_xor(lt, 16, 64);
  lt += __shfl_xor(lt, 32, 64);

  int b = bh >> 4;
  if (gx < 63) {
#pragma unroll
    for (int reg = 0; reg < 4; ++reg) {
      float ls = __shfl(lt, 4 * g + reg, 64);
      float rl = 1.0f / ls;
      int row = qb * 64 + w * 16 + 4 * g + reg;
#pragma unroll
      for (int dt = 0; dt < 4; ++dt) {
        int col = h * 64 + dt * 16 + q;
        attn_out[((size_t)b * 4096 + row) * 1024 + col] = f2bf(accO[dt][reg] * rl);
      }
    }
  } else {
    int chunk = gx - 63;
    float* Op = Opart + (size_t)(bh * 8 + chunk) * 64 * 64;
    float* lp = lpart + (size_t)(bh * 8 + chunk) * 64;
#pragma unroll
    for (int reg = 0; reg < 4; ++reg) {
      int row = w * 16 + 4 * g + reg;
#pragma unroll
      for (int dt = 0; dt < 4; ++dt) {
        int col = dt * 16 + q;
        Op[row * 64 + col] = accO[dt][reg];
      }
    }
    if (g == 0) lp[w * 16 + q] = lt;
  }
}

// ---------------- merge the 8 qb=0 chunks ----------------
__global__ void merge_qb0(const float* __restrict__ Opart, const float* __restrict__ lpart,
                          unsigned short* __restrict__ attn_out) {
  int bh = blockIdx.x;
  int tid = threadIdx.x;
  int row = tid >> 2, cg = tid & 3;
  const float* lp = lpart + (size_t)bh * 8 * 64;
  float L = 0.f;
#pragma unroll
  for (int c = 0; c < 8; ++c) L += lp[c * 64 + row];
  float rL = 1.0f / L;
  int b = bh >> 4, h = bh & 15;
  f32x4 acc0 = {}, acc1 = {}, acc2 = {}, acc3 = {};
#pragma unroll
  for (int c = 0; c < 8; ++c) {
    const float* Op = Opart + ((size_t)(bh * 8 + c) * 64 + row) * 64 + cg * 16;
    acc0 += ((const f32x4*)Op)[0];
    acc1 += ((const f32x4*)Op)[1];
    acc2 += ((const f32x4*)Op)[2];
    acc3 += ((const f32x4*)Op)[3];
  }
  unsigned short* out = attn_out + ((size_t)b * 4096 + row) * 1024 + h * 64 + cg * 16;
#pragma unroll
  for (int j = 0; j < 4; ++j) {
    out[j] = f2bf(acc0[j] * rL);
    out[4 + j] = f2bf(acc1[j] * rL);
    out[8 + j] = f2bf(acc2[j] * rL);
    out[12 + j] = f2bf(acc3[j] * rL);
  }
}

extern "C" void kernel_launch(void* const* d_in, const int* in_sizes, int n_in,
                              void* d_out, int out_size, void* d_ws, size_t ws_size,
                              hipStream_t stream) {
  const float* x = (const float*)d_in[0];
  const float* Wq = (const float*)d_in[1];
  const float* Wk = (const float*)d_in[2];
  const float* Wv = (const float*)d_in[3];
  const float* Wo = (const float*)d_in[4];
  const int* bidx = (const int*)d_in[5];

  char* ws = (char*)d_ws;
  unsigned short* xb = (unsigned short*)(ws);
  unsigned short* wt = (unsigned short*)(ws + 16777216);
  unsigned short* Qb = (unsigned short*)(ws + 25165824);
  unsigned short* Kb = (unsigned short*)(ws + 41943040);
  unsigned short* Vtb = (unsigned short*)(ws + 58720256);
  unsigned short* attnb = (unsigned short*)(ws + 75497472);
  float* Opart = (float*)(ws);
  float* lpart = (float*)(ws + 4194304);

  prep_kernel<<<5120, 256, 0, stream>>>(x, xb, Wq, Wk, Wv, Wo, wt);
  gemm_qkv<<<dim3(24, 64), 256, 0, stream>>>(xb, wt, Qb, Kb, Vtb, 0.18033688f);
  attn_kernel<<<dim3(71, 32), 256, 0, stream>>>(Qb, Kb, Vtb, bidx, attnb, Opart, lpart);
  merge_qb0<<<32, 256, 0, stream>>>(Opart, lpart, attnb);
  gemm_out<<<dim3(8, 64), 256, 0, stream>>>(attnb, wt + 3145728, (float*)d_out);
}